// Round 2
// baseline (12795.774 us; speedup 1.0000x reference)
//
#include <hip/hip_runtime.h>
#include <hip/hip_bf16.h>

using bf16 = __hip_bfloat16;

__device__ __forceinline__ float b2f(bf16 x){ return __bfloat162float(x); }
__device__ __forceinline__ bf16  f2b(float x){ return __float2bfloat16(x); }

// ---------------- problem constants (fixed by setup_inputs) ----------------
constexpr int Mmol = 512, Aat = 64;
constexpr int Nat  = Mmol * Aat;      // 32768 real atoms
constexpr int NP1  = Nat + 1;         // 32769 rows (padding row 0)
constexpr int Bnd  = Nat * 4;         // 131072 directed bonds
constexpr int BP1  = Bnd + 1;         // 131073 rows
constexpr int Hd   = 300;
constexpr int AF   = 133, BFd = 147;
constexpr int NB   = 6;

// =====================================================================
// Generic tiled f32 GEMM:  C[n,h] = act( Asrc[n,k] @ W[h,k]^T (+bias)(+res) )
// All weights W are float32 (as passed by the harness). A-operand modes:
//   0 = bf16 A direct (workspace tensors stored bf16)
//   1 = f32 A direct
//   2 = f32 A with relu-on-load
//   3 = gathered A(row,kk) = A2[g1[row]*300+kk] - bf16 GB[g2[row]*300+kk]  (k==300)
//   4 = concat3 f32: kk<300 -> A, kk<600 -> A2, else A3 (row-stride 300, k==900)
// =====================================================================
constexpr int BMr = 256, BNc = 64, BKk = 8;

template<int AMODE, bool RELU, bool BIAS, bool RES, bool OUTBF16>
__global__ __launch_bounds__(256) void gemm_k(
    const void* __restrict__ A, const float* __restrict__ A2, const float* __restrict__ A3,
    const bf16* __restrict__ GB, const int* __restrict__ g1, const int* __restrict__ g2,
    const float* __restrict__ W, const float* __restrict__ bias, const bf16* __restrict__ res,
    void* __restrict__ Cp, int n, int k, int h)
{
    __shared__ float As[BMr][12];   // stride 12 words: b128-aligned, low-conflict
    __shared__ float Ws[BKk][BNc];

    const int tid = threadIdx.x;
    const int tx = tid & 15, ty = tid >> 4;
    const long rowBase = (long)blockIdx.x * BMr;
    const long colBase = (long)blockIdx.y * BNc;

    const long grow = rowBase + tid;      // this thread's A row for staging
    const bool rv = grow < n;
    long ra = 0, rb = 0;
    if constexpr (AMODE == 3) {
        ra = rv ? (long)g1[grow] : 0;
        rb = rv ? (long)g2[grow] : 0;
    }

    const int wcol = tid & 63, kh = tid >> 6;   // W staging: 64 cols x (4 groups of 2 kk)
    const long gcol = colBase + wcol;
    const bool cvv = gcol < h;

    float acc[16][4];
    #pragma unroll
    for (int i = 0; i < 16; ++i) { acc[i][0]=0.f; acc[i][1]=0.f; acc[i][2]=0.f; acc[i][3]=0.f; }

    for (int kb = 0; kb < k; kb += BKk) {
        __syncthreads();
        // ---- stage A tile: each thread stages one row x 8 kk ----
        float av[8];
        #pragma unroll
        for (int c = 0; c < 8; ++c) {
            const int kk = kb + c;
            float v = 0.f;
            if (rv && kk < k) {
                if constexpr (AMODE == 0) {
                    v = b2f(((const bf16*)A)[grow * (long)k + kk]);
                } else if constexpr (AMODE == 1) {
                    v = ((const float*)A)[grow * (long)k + kk];
                } else if constexpr (AMODE == 2) {
                    v = fmaxf(((const float*)A)[grow * (long)k + kk], 0.f);
                } else if constexpr (AMODE == 3) {
                    v = A2[ra * 300 + kk] - b2f(GB[rb * 300 + kk]);
                } else if constexpr (AMODE == 4) {
                    v = (kk < 300) ? ((const float*)A)[grow * 300 + kk]
                      : (kk < 600) ? A2[grow * 300 + (kk - 300)]
                                   : A3[grow * 300 + (kk - 600)];
                }
            }
            av[c] = v;
        }
        *(float4*)&As[tid][0] = make_float4(av[0], av[1], av[2], av[3]);
        *(float4*)&As[tid][4] = make_float4(av[4], av[5], av[6], av[7]);
        // ---- stage W tile ----
        #pragma unroll
        for (int c = 0; c < 2; ++c) {
            const int kk = kb + kh * 2 + c;
            const float wv = (cvv && kk < k) ? W[gcol * (long)k + kk] : 0.f;
            Ws[kh * 2 + c][wcol] = wv;
        }
        __syncthreads();
        // ---- compute 16x4 micro-tile over 8 kk ----
        #pragma unroll
        for (int kk = 0; kk < BKk; ++kk) {
            const float4 bv = *(const float4*)&Ws[kk][tx * 4];
            #pragma unroll
            for (int i = 0; i < 16; ++i) {
                const float a = As[ty + i * 16][kk];
                acc[i][0] = fmaf(a, bv.x, acc[i][0]);
                acc[i][1] = fmaf(a, bv.y, acc[i][1]);
                acc[i][2] = fmaf(a, bv.z, acc[i][2]);
                acc[i][3] = fmaf(a, bv.w, acc[i][3]);
            }
        }
    }
    // ---- epilogue ----
    #pragma unroll
    for (int i = 0; i < 16; ++i) {
        const long r = rowBase + ty + i * 16;
        if (r < n) {
            #pragma unroll
            for (int j = 0; j < 4; ++j) {
                const long c = colBase + tx * 4 + j;
                if (c < h) {
                    float v = acc[i][j];
                    if constexpr (RES)  v += b2f(res[r * (long)h + c]);
                    if constexpr (BIAS) v += bias[c];
                    if constexpr (RELU) v = fmaxf(v, 0.f);
                    if constexpr (OUTBF16) ((bf16*)Cp)[r * (long)h + c] = f2b(v);
                    else                   ((float*)Cp)[r * (long)h + c] = v;
                }
            }
        }
    }
}

// =====================================================================
// agg: out[row] = (src[atom]?) + sum_j(MB[a2b[atom][j]]) * max_j(MB[a2b[atom][j]])
// atom = blockIdx.x + rowoff ; out row = blockIdx.x
// =====================================================================
template<bool ADD>
__global__ __launch_bounds__(320) void agg_kernel(
    const bf16* __restrict__ MB, const int* __restrict__ a2b,
    const float* __restrict__ src, float* __restrict__ out, int rowoff)
{
    const int hh = threadIdx.x;
    if (hh >= Hd) return;
    const long atom = (long)blockIdx.x + rowoff;
    const int* nb = a2b + atom * NB;
    float s = 0.f, mx = -1e30f;
    #pragma unroll
    for (int j = 0; j < NB; ++j) {
        const float v = b2f(MB[(long)nb[j] * Hd + hh]);
        s += v; mx = fmaxf(mx, v);
    }
    const float agg = s * mx;
    const long o = (long)blockIdx.x * Hd + hh;
    if constexpr (ADD) out[o] = src[atom * Hd + hh] + agg;
    else               out[o] = agg;
}

// h0[m][hh] = max_a node[m*64+a][hh]   (node is pre-relu)
__global__ __launch_bounds__(320) void h0_kernel(const float* __restrict__ node, float* __restrict__ h0)
{
    const int hh = threadIdx.x;
    if (hh >= Hd) return;
    const long m = blockIdx.x;
    float mx = -1e30f;
    for (int a = 0; a < Aat; ++a)
        mx = fmaxf(mx, node[(m * Aat + a) * (long)Hd + hh]);
    h0[m * Hd + hh] = mx;
}

// out[m][hh] = mean_a AH[m*64+a][hh]  -> f32 d_out
__global__ __launch_bounds__(320) void mean_kernel(const float* __restrict__ AH, float* __restrict__ out)
{
    const int hh = threadIdx.x;
    if (hh >= Hd) return;
    const long m = blockIdx.x;
    float s = 0.f;
    for (int a = 0; a < Aat; ++a)
        s += AH[(m * Aat + a) * (long)Hd + hh];
    out[m * Hd + hh] = s * (1.f / 64.f);
}

// =====================================================================
// Bidirectional batched GRU: one block = 4 molecules x 1 direction.
// h kept in LDS; gh = Whh @ h + bhh recomputed per step (Whh f32 streamed from L2).
// torch gate order (r,z,n): r=sig(ir+hr) z=sig(iz+hz) n=tanh(inn + r*hn)
// h' = (1-z)*n + z*h.  fwd writes out[row][0:300], bwd writes out[row][300:600].
// =====================================================================
constexpr int GRU_G = 4;

__global__ __launch_bounds__(256) void gru_kernel(
    const bf16* __restrict__ gi_f, const bf16* __restrict__ gi_b,
    const float* __restrict__ Whh_f, const float* __restrict__ Whh_b,
    const float* __restrict__ bhh_f, const float* __restrict__ bhh_b,
    const float* __restrict__ h0, bf16* __restrict__ out)
{
    const int dir = blockIdx.x & 1;
    const int m0  = (blockIdx.x >> 1) * GRU_G;
    const float* Whh = dir ? Whh_b : Whh_f;
    const float* bhh = dir ? bhh_b : bhh_f;
    const bf16*  gi  = dir ? gi_b  : gi_f;

    __shared__ float Hs[GRU_G][304];
    __shared__ float GHs[GRU_G][904];
    const int tid = threadIdx.x;

    for (int idx = tid; idx < GRU_G * Hd; idx += 256) {
        const int g = idx / Hd, hh = idx - g * Hd;
        Hs[g][hh] = h0[(long)(m0 + g) * Hd + hh];
    }
    __syncthreads();

    for (int t = 0; t < Aat; ++t) {
        // ---- phase 1: gh[j] = dot(Whh[j,:], h[g,:]) for j in [0,900) ----
        float acc[4][GRU_G];
        #pragma unroll
        for (int r = 0; r < 4; ++r)
            #pragma unroll
            for (int g = 0; g < GRU_G; ++g) acc[r][g] = 0.f;

        for (int k4 = 0; k4 < Hd / 4; ++k4) {
            float4 hv[GRU_G];
            #pragma unroll
            for (int g = 0; g < GRU_G; ++g) hv[g] = *(const float4*)&Hs[g][k4 * 4];
            #pragma unroll
            for (int r = 0; r < 4; ++r) {
                const int j = r * 256 + tid;
                if (j < 900) {
                    const float4 w = *(const float4*)(Whh + (long)j * Hd + k4 * 4);
                    #pragma unroll
                    for (int g = 0; g < GRU_G; ++g) {
                        acc[r][g] = fmaf(w.x, hv[g].x, acc[r][g]);
                        acc[r][g] = fmaf(w.y, hv[g].y, acc[r][g]);
                        acc[r][g] = fmaf(w.z, hv[g].z, acc[r][g]);
                        acc[r][g] = fmaf(w.w, hv[g].w, acc[r][g]);
                    }
                }
            }
        }
        #pragma unroll
        for (int r = 0; r < 4; ++r) {
            const int j = r * 256 + tid;
            if (j < 900) {
                const float bb = bhh[j];
                #pragma unroll
                for (int g = 0; g < GRU_G; ++g) GHs[g][j] = acc[r][g] + bb;
            }
        }
        __syncthreads();
        // ---- phase 2: gates + state update + output ----
        const int a = dir ? (Aat - 1 - t) : t;
        for (int idx = tid; idx < GRU_G * Hd; idx += 256) {
            const int g = idx / Hd, hh = idx - g * Hd;
            const long row = (long)(m0 + g) * Aat + a;
            const bf16* girow = gi + row * 900;
            const float ir  = b2f(girow[hh]);
            const float iz  = b2f(girow[300 + hh]);
            const float inn = b2f(girow[600 + hh]);
            const float hr = GHs[g][hh], hz = GHs[g][300 + hh], hn = GHs[g][600 + hh];
            const float rr = 1.f / (1.f + __expf(-(ir + hr)));
            const float zz = 1.f / (1.f + __expf(-(iz + hz)));
            float nin = inn + rr * hn;
            nin = fminf(fmaxf(nin, -15.f), 15.f);
            const float e2 = __expf(-2.f * nin);
            const float nn = (1.f - e2) / (1.f + e2);
            const float hold = Hs[g][hh];
            const float hnew = (1.f - zz) * nn + zz * hold;
            Hs[g][hh] = hnew;                                   // own element only: safe
            out[row * 600 + (long)dir * 300 + hh] = f2b(hnew);
        }
        __syncthreads();
    }
}

// =====================================================================
extern "C" void kernel_launch(void* const* d_in, const int* in_sizes, int n_in,
                              void* d_out, int out_size, void* d_ws, size_t ws_size,
                              hipStream_t stream)
{
    (void)in_sizes; (void)n_in; (void)out_size; (void)ws_size;

    const float* f_atoms  = (const float*)d_in[0];
    const float* f_bonds  = (const float*)d_in[1];
    const int*   a2b      = (const int*)d_in[2];
    const int*   b2a      = (const int*)d_in[3];
    const int*   b2revb   = (const int*)d_in[4];
    const float* W_i_atom = (const float*)d_in[7];
    const float* W_i_bond = (const float*)d_in[8];
    const float* W_h      = (const float*)d_in[9];    // [2,300,300]
    const float* lr_W     = (const float*)d_in[10];   // [300,900]
    const float* W_o_W    = (const float*)d_in[11];   // [300,600]
    const float* W_o_b    = (const float*)d_in[12];
    const float* gWih_f   = (const float*)d_in[13];
    const float* gWhh_f   = (const float*)d_in[14];
    const float* gbih_f   = (const float*)d_in[15];
    const float* gbhh_f   = (const float*)d_in[16];
    const float* gWih_b   = (const float*)d_in[17];
    const float* gWhh_b   = (const float*)d_in[18];
    const float* gbih_b   = (const float*)d_in[19];
    const float* gbhh_b   = (const float*)d_in[20];

    // ---- workspace layout (bump + liveness overlap; peak ~237 MB) ----
    const size_t IA_B   = (size_t)NP1 * Hd * 4;     // f32 atom tensors
    const size_t IB_B   = (size_t)BP1 * Hd * 2;     // bf16 bond tensors
    const size_t NODE_B = (size_t)Nat * Hd * 4;     // f32
    const size_t H0_B   = (size_t)Mmol * Hd * 4;

    size_t off = 0;
    auto alloc = [&](size_t b) { size_t r = off; off += (b + 255) & ~(size_t)255; return r; };
    const size_t ia_o = alloc(IA_B);
    const size_t ma_o = alloc(IA_B);
    const size_t r2_o = alloc(IB_B);   // IB -> MB1(in-place) -> gi_f -> AH
    const size_t r3_o = alloc(IB_B);   // MB0 -> (AGG | NODE) -> (gru_out | NODE)
    const size_t h0_o = alloc(H0_B);

    char* ws = (char*)d_ws;
    float* IA   = (float*)(ws + ia_o);
    float* MAb  = (float*)(ws + ma_o);
    bf16*  IB   = (bf16*)(ws + r2_o);
    bf16*  MB0  = (bf16*)(ws + r3_o);
    bf16*  MB1  = IB;                          // d=1 writes in place over IB
    float* AGG  = (float*)(ws + r3_o);         // after MB0 dead
    float* NODE = (float*)(ws + r3_o + NODE_B);
    bf16*  GIF  = (bf16*)(ws + r2_o);          // after MB1 dead (MB1 last read step 7)
    bf16*  GIB  = (bf16*)(ws + ia_o);          // after IA/MA dead (last read step 8)
    bf16*  GRU  = (bf16*)(ws + r3_o);          // over dead AGG; NODE untouched
    float* H0p  = (float*)(ws + h0_o);
    float* AH   = (float*)(ws + r2_o);         // over gi_f after GRU consumed it
    float* OUT  = (float*)d_out;

    const dim3 blk(256);
    auto grd = [](int n, int h) { return dim3((n + BMr - 1) / BMr, (h + BNc - 1) / BNc); };

    // 1. input_atom = relu(f_atoms @ W_i_atom^T)  -> f32
    gemm_k<1, true, false, false, false><<<grd(NP1, Hd), blk, 0, stream>>>(
        f_atoms, nullptr, nullptr, nullptr, nullptr, nullptr, W_i_atom, nullptr, nullptr,
        IA, NP1, AF, Hd);
    // 2. input_bond = relu(f_bonds @ W_i_bond^T)  -> bf16
    gemm_k<1, true, false, false, true><<<grd(BP1, Hd), blk, 0, stream>>>(
        f_bonds, nullptr, nullptr, nullptr, nullptr, nullptr, W_i_bond, nullptr, nullptr,
        IB, BP1, BFd, Hd);
    // 3. d=0 atom agg: MA = IA + sum*max(IB gathered)
    agg_kernel<true><<<NP1, 320, 0, stream>>>(IB, a2b, IA, MAb, 0);
    // 4. d=0 bond update: MB0 = relu(IB + (MA[b2a]-IB[b2revb]) @ Wh0^T)
    gemm_k<3, true, false, true, true><<<grd(BP1, Hd), blk, 0, stream>>>(
        nullptr, MAb, nullptr, IB, b2a, b2revb, W_h, nullptr, IB,
        MB0, BP1, Hd, Hd);
    // 5. d=1 atom agg: MA += sum*max(MB0 gathered)
    agg_kernel<true><<<NP1, 320, 0, stream>>>(MB0, a2b, MAb, MAb, 0);
    // 6. d=1 bond update: MB1(=IB region) = relu(IB + (MA[b2a]-MB0[b2revb]) @ Wh1^T)
    gemm_k<3, true, false, true, true><<<grd(BP1, Hd), blk, 0, stream>>>(
        nullptr, MAb, nullptr, MB0, b2a, b2revb, W_h + 300 * 300, nullptr, IB,
        MB1, BP1, Hd, Hd);
    // 7. final agg for atoms 1..N -> AGG
    agg_kernel<false><<<Nat, 320, 0, stream>>>(MB1, a2b, nullptr, AGG, 1);
    // 8. node = concat(AGG, MA, IA) @ lr_W^T   (pre-relu, atoms 1..N)
    gemm_k<4, false, false, false, false><<<grd(Nat, Hd), blk, 0, stream>>>(
        AGG, MAb + Hd, IA + Hd, nullptr, nullptr, nullptr, lr_W, nullptr, nullptr,
        NODE, Nat, 900, Hd);
    // 9. h0 = per-mol max of pre-relu node
    h0_kernel<<<Mmol, 320, 0, stream>>>(NODE, H0p);
    // 10/11. gi = relu(node) @ gWih^T + gbih  -> bf16
    gemm_k<2, false, true, false, true><<<grd(Nat, 900), blk, 0, stream>>>(
        NODE, nullptr, nullptr, nullptr, nullptr, nullptr, gWih_f, gbih_f, nullptr,
        GIF, Nat, Hd, 900);
    gemm_k<2, false, true, false, true><<<grd(Nat, 900), blk, 0, stream>>>(
        NODE, nullptr, nullptr, nullptr, nullptr, nullptr, gWih_b, gbih_b, nullptr,
        GIB, Nat, Hd, 900);
    // 12. bidirectional GRU scan -> bf16 [Nat, 600]
    gru_kernel<<<(Mmol / GRU_G) * 2, 256, 0, stream>>>(
        GIF, GIB, gWhh_f, gWhh_b, gbhh_f, gbhh_b, H0p, GRU);
    // 13. atom_hiddens = relu(gru_out @ W_o_W^T + W_o_b) -> f32 (atoms 1..N)
    gemm_k<0, true, true, false, false><<<grd(Nat, Hd), blk, 0, stream>>>(
        GRU, nullptr, nullptr, nullptr, nullptr, nullptr, W_o_W, W_o_b, nullptr,
        AH, Nat, 600, Hd);
    // 14. mol_vecs = mean over atoms -> f32 d_out
    mean_kernel<<<Mmol, 320, 0, stream>>>(AH, OUT);
}